// Round 7
// baseline (7363.553 us; speedup 1.0000x reference)
//
#include <hip/hip_runtime.h>
#include <math.h>

// Problem constants (fixed by reference)
#define T   1024
#define NB  16
#define HD  512

// ws layout (float offsets)
#define OFF_BAR  0                         // 256 ints: flag[2][128] step counters
#define OFF_HH   256                       // h_hist [2][T][NB][HD] = 16,777,216 floats
#define OFF_SH   (OFF_HH + 16777216)       // SH [16384][512] = 8,388,608 floats
#define OFF_SEGP (OFF_SH + 8388608)        // [16384]
#define OFF_GCTX (OFF_SEGP + 16384)        // [16][1024]
#define OFF_SEL  (OFF_GCTX + 16384)        // ints [16][12]

typedef unsigned long long u64;
typedef __attribute__((address_space(1))) const unsigned int gu32_t;
typedef __attribute__((address_space(3))) unsigned int lu32_t;

__device__ __forceinline__ float sigmoidf_(float x){ return 1.0f/(1.0f + __expf(-x)); }
// fast tanh via exp2-based __expf; |err| ~1e-7, graceful saturation at +/-1
__device__ __forceinline__ float tanhf_(float x){ return 1.0f - 2.0f/(1.0f + __expf(2.0f*x)); }

// ---------------------------------------------------------------------------
// Persistent bidirectional LSTM. grid=256 wgs (1 per CU), block=512 (8 waves).
// wg -> (dir = wg&1, slice = wg>>1 of 4 hidden units). Weights in VGPRs/AGPRs.
// Structure = round 4 (proven fastest): 2 block barriers/step, LDS gbuf gate
// exchange, wave0 gates, sc1 h-store + vmcnt ack + per-wg flag, wave0 polls.
//
// NEW vs r4: the x-gather (instr -> emb row, dependent ~900cy chain) is moved
// OFF the top-of-step critical path via async global_load_lds staging:
//   end of step s (AFTER the flag store, so the producer ack never covers it):
//   waves 1..7 issue 32 x global_load_lds(16B) filling x_lds[(s+1)&1] (32KB).
//   The gather latency drains during the next poll window (non-wave0 waves'
//   vmcnt(0) runs concurrently with wave0's poll; wave0 issues no fills so its
//   poll start is never delayed).
// Global source addresses are pre-swizzled so x-proj reads are two stride-16B
// ds_read_b128 per batch: LDS layout [b][half][pos], chunk c = 2*pos + half.
// ---------------------------------------------------------------------------
__global__ __launch_bounds__(512, 1)
void lstm_kernel(const int* __restrict__ instr, const float* __restrict__ emb,
                 const float* __restrict__ wih_f, const float* __restrict__ whh_f,
                 const float* __restrict__ bih_f, const float* __restrict__ bhh_f,
                 const float* __restrict__ wih_b, const float* __restrict__ whh_b,
                 const float* __restrict__ bih_b, const float* __restrict__ bhh_b,
                 float* __restrict__ ws)
{
    float* h_hist = ws + OFF_HH;
    int* flags = (int*)ws;            // flag[2][128]

    const int wg    = blockIdx.x;     // 0..255
    const int dir   = wg & 1;
    const int slice = wg >> 1;        // 0..127
    const int U     = slice * 4;      // hidden-unit base

    int* barf = flags + dir*128;

    const float* wih = dir ? wih_b : wih_f;
    const float* whh = dir ? whh_b : whh_f;
    const float* bih = dir ? bih_b : bih_f;
    const float* bhh = dir ? bhh_b : bhh_f;

    const int tid  = threadIdx.x;
    const int wid  = tid >> 6;        // 0..7
    const int lane = tid & 63;        // k-chunk id (8 k's per lane)
    const int bg   = wid >> 1;        // 0..3 : batches bg*4..bg*4+3
    const int rg   = wid & 1;         // 0..1 : local gate-rows rg*8..rg*8+7

    // x staging: double-buffered swizzled tile [2][16 b][2 half][64 pos][4]
    __shared__ float x_lds[2][8192];  // 2 x 32KB
    __shared__ float gbuf[256];

    // ---- fill issue: waves 1..7 cover q = 0..31 (q = j*7 + wid-1), b = q>>1
    // LDS slot for (q, lane) = q*1024B + lane*16B (linear dest); global source
    // emb[idx[b]*512 + (2*lane + (q&1))*4 .. +4) (pre-swizzled chunk).
#define ISSUE_FILLS(BUF, TN)                                                        \
    if (wid > 0){                                                                   \
        float* dstb = &x_lds[BUF][0];                                               \
        _Pragma("unroll")                                                           \
        for (int j = 0; j < 5; ++j){                                                \
            int q = j*7 + wid - 1;                                                  \
            if (q < 32){                                                            \
                int b_ = q >> 1;                                                    \
                int idxv = instr[b_*T + (TN)];                                      \
                const float* src = emb + (size_t)idxv*HD + (2*lane + (q&1))*4;      \
                __builtin_amdgcn_global_load_lds((gu32_t*)(const void*)src,         \
                    (lu32_t*)(void*)(dstb + q*256), 16, 0, 0);                      \
            }                                                                       \
        }                                                                           \
    }

    // Prologue: stage x for step 0 (overlaps weight loading below)
    {
        int t0 = dir ? (T-1) : 0;
        ISSUE_FILLS(0, t0)
    }

    // Load weight slices into registers: local row (rg*8+ri), k = lane*8..+8
    float wi[64], wh[64];
#pragma unroll
    for (int ri = 0; ri < 8; ++ri){
        int rgl = rg*8 + ri;
        int gate = rgl >> 2, unit = rgl & 3;
        size_t row = (size_t)(gate*HD + U + unit) * HD + lane*8;
        float4 a0 = *(const float4*)(wih + row);
        float4 a1 = *(const float4*)(wih + row + 4);
        float4 b0 = *(const float4*)(whh + row);
        float4 b1 = *(const float4*)(whh + row + 4);
        wi[ri*8+0]=a0.x; wi[ri*8+1]=a0.y; wi[ri*8+2]=a0.z; wi[ri*8+3]=a0.w;
        wi[ri*8+4]=a1.x; wi[ri*8+5]=a1.y; wi[ri*8+6]=a1.z; wi[ri*8+7]=a1.w;
        wh[ri*8+0]=b0.x; wh[ri*8+1]=b0.y; wh[ri*8+2]=b0.z; wh[ri*8+3]=b0.w;
        wh[ri*8+4]=b1.x; wh[ri*8+5]=b1.y; wh[ri*8+6]=b1.z; wh[ri*8+7]=b1.w;
    }

    // Biases for owner lanes (tid<64 owns (b=tid>>2, u=tid&3))
    float bI, bF, bG, bO, cst = 0.0f;
    {
        int u = tid & 3;
        bI = bih[0*HD + U + u] + bhh[0*HD + U + u];
        bF = bih[1*HD + U + u] + bhh[1*HD + U + u];
        bG = bih[2*HD + U + u] + bhh[2*HD + U + u];
        bO = bih[3*HD + U + u] + bhh[3*HD + U + u];
    }

    // reduce-scatter ownership (32 values, 5 xor stages + cross-half merge):
    const int jown = ((lane&1)<<4)|((lane&2)<<2)|(lane&4)|((lane&8)>>2)|((lane&16)>>4);
    const int own_bi  = jown >> 3;            // 0..3
    const int own_rgl = rg*8 + (jown & 7);    // 0..15
    const int gslot   = (own_rgl >> 2)*64 + (bg*4 + own_bi)*4 + (own_rgl & 3);

    // drain prologue fills, make them LDS-visible block-wide
    asm volatile("s_waitcnt vmcnt(0)" ::: "memory");
    __builtin_amdgcn_sched_barrier(0);
    __syncthreads();

    for (int s = 0; s < T; ++s){
        const int tp = dir ? (T-1-s) : s;   // original-time index
        const int cur = s & 1;

        // ---- wait for step s-1 of all 128 wgs in this direction
        if (s > 0){
            if (wid == 0){
                for (;;){
                    int v0 = __hip_atomic_load(barf + lane,      __ATOMIC_RELAXED, __HIP_MEMORY_SCOPE_AGENT);
                    int v1 = __hip_atomic_load(barf + 64 + lane, __ATOMIC_RELAXED, __HIP_MEMORY_SCOPE_AGENT);
                    if (__all((v0 >= s) && (v1 >= s))) break;
                    __builtin_amdgcn_s_sleep(1);
                }
            }
            // each wave drains its own fills (waves 1..7 do this during wave0's poll)
            asm volatile("s_waitcnt vmcnt(0)" ::: "memory");
            __builtin_amdgcn_sched_barrier(0);
            __syncthreads();   // fills visible block-wide; releases waves 1..7
        }

        float a[32];
#pragma unroll
        for (int j = 0; j < 32; ++j) a[j] = 0.0f;

        if (s > 0){
            // ---- issue ALL h loads first (coalesced 32B/lane), then overlap
            //      x-proj (LDS) with their flight; h-proj as they drain.
            const int tprev = dir ? (T - s) : (s - 1);
            const float* hbase = h_hist + (size_t)(dir*T + tprev)*NB*HD;
            const float* p0 = hbase + (size_t)(bg*4 + 0)*HD + lane*8;
            const float* p1 = hbase + (size_t)(bg*4 + 1)*HD + lane*8;
            const float* p2 = hbase + (size_t)(bg*4 + 2)*HD + lane*8;
            const float* p3 = hbase + (size_t)(bg*4 + 3)*HD + lane*8;
            float4 h00 = *(const float4*)p0, h01 = *(const float4*)(p0+4);
            float4 h10 = *(const float4*)p1, h11 = *(const float4*)(p1+4);
            float4 h20 = *(const float4*)p2, h21 = *(const float4*)(p2+4);
            float4 h30 = *(const float4*)p3, h31 = *(const float4*)(p3+4);

            // ---- x-proj from staged LDS (no global latency)
            const float* xl = &x_lds[cur][0];
#pragma unroll
            for (int bi = 0; bi < 4; ++bi){
                int b = bg*4 + bi;
                float4 x0 = *(const float4*)&xl[b*512 + lane*4];
                float4 x1 = *(const float4*)&xl[b*512 + 256 + lane*4];
                float xs[8] = {x0.x,x0.y,x0.z,x0.w,x1.x,x1.y,x1.z,x1.w};
#pragma unroll
                for (int kk = 0; kk < 8; ++kk){
                    float xv = xs[kk];
#pragma unroll
                    for (int ri = 0; ri < 8; ++ri)
                        a[bi*8+ri] = fmaf(xv, wi[ri*8+kk], a[bi*8+ri]);
                }
            }

            // ---- h-proj
            {
                float hs0[8] = {h00.x,h00.y,h00.z,h00.w,h01.x,h01.y,h01.z,h01.w};
                float hs1[8] = {h10.x,h10.y,h10.z,h10.w,h11.x,h11.y,h11.z,h11.w};
#pragma unroll
                for (int kk = 0; kk < 8; ++kk){
#pragma unroll
                    for (int ri = 0; ri < 8; ++ri){
                        a[0*8+ri] = fmaf(hs0[kk], wh[ri*8+kk], a[0*8+ri]);
                        a[1*8+ri] = fmaf(hs1[kk], wh[ri*8+kk], a[1*8+ri]);
                    }
                }
            }
            {
                float hs2[8] = {h20.x,h20.y,h20.z,h20.w,h21.x,h21.y,h21.z,h21.w};
                float hs3[8] = {h30.x,h30.y,h30.z,h30.w,h31.x,h31.y,h31.z,h31.w};
#pragma unroll
                for (int kk = 0; kk < 8; ++kk){
#pragma unroll
                    for (int ri = 0; ri < 8; ++ri){
                        a[2*8+ri] = fmaf(hs2[kk], wh[ri*8+kk], a[2*8+ri]);
                        a[3*8+ri] = fmaf(hs3[kk], wh[ri*8+kk], a[3*8+ri]);
                    }
                }
            }
        } else {
            // s==0: x-proj only (h0 = 0)
            const float* xl = &x_lds[cur][0];
#pragma unroll
            for (int bi = 0; bi < 4; ++bi){
                int b = bg*4 + bi;
                float4 x0 = *(const float4*)&xl[b*512 + lane*4];
                float4 x1 = *(const float4*)&xl[b*512 + 256 + lane*4];
                float xs[8] = {x0.x,x0.y,x0.z,x0.w,x1.x,x1.y,x1.z,x1.w};
#pragma unroll
                for (int kk = 0; kk < 8; ++kk){
                    float xv = xs[kk];
#pragma unroll
                    for (int ri = 0; ri < 8; ++ri)
                        a[bi*8+ri] = fmaf(xv, wi[ri*8+kk], a[bi*8+ri]);
                }
            }
        }

        // ---- reduce-scatter: 32 values over 64 lanes (5 stages + merge)
#pragma unroll
        for (int m = 0; m < 5; ++m){
            const int half = 16 >> m;
            const bool up = (lane >> m) & 1;
#pragma unroll
            for (int j = 0; j < 16; ++j){
                if (j < half){
                    float lo = a[j], hi = a[j+half];
                    float rlo = __shfl_xor(lo, 1<<m, 64);
                    float rhi = __shfl_xor(hi, 1<<m, 64);
                    a[j] = up ? (hi + rhi) : (lo + rlo);
                }
            }
        }
        a[0] += __shfl_xor(a[0], 32, 64);   // cross-half k merge

        if ((lane & 32) == 0) gbuf[gslot] = a[0];
        __syncthreads();

        if (tid < 64){   // wave-uniform branch: wave0 only
            float iv = sigmoidf_(gbuf[      tid] + bI);
            float fv = sigmoidf_(gbuf[ 64 + tid] + bF);
            float gv = tanhf_  (gbuf[128 + tid] + bG);
            float ov = sigmoidf_(gbuf[192 + tid] + bO);
            cst = fv*cst + iv*gv;
            float hv = ov * tanhf_(cst);
            int b = tid >> 2, u = tid & 3;
            // sc1 store: reaches LLC (bypasses local L2) before the flag
            __hip_atomic_store(&h_hist[((size_t)(dir*T + tp)*NB + b)*HD + U + u], hv,
                               __ATOMIC_RELAXED, __HIP_MEMORY_SCOPE_AGENT);
        }
        // producer ack: ONLY h stores outstanding here (fills issue after flag)
        asm volatile("s_waitcnt vmcnt(0)" ::: "memory");
        __builtin_amdgcn_sched_barrier(0);
        if (tid == 0)
            __hip_atomic_store(barf + slice, s + 1, __ATOMIC_RELAXED, __HIP_MEMORY_SCOPE_AGENT);

        // ---- stage x for step s+1 (latency drains during next poll window)
        if (s + 1 < T){
            int tn = dir ? (T-2-s) : (s+1);
            ISSUE_FILLS(cur ^ 1, tn)
        }
    }
}

// ---------------------------------------------------------------------------
// SH = relu(enc @ ws1.T + bs1)   M=16384 N=512 K=1024, fp32 64x64x16 tiles
// ---------------------------------------------------------------------------
__global__ __launch_bounds__(256, 2)
void seg_gemm(const float* __restrict__ ws_, const float* __restrict__ ws1,
              const float* __restrict__ bs1)
{
    const float* h_hist = ws_ + OFF_HH;
    float* SH = (float*)(ws_ + OFF_SH);
    __shared__ float As[64][17];
    __shared__ float Bs[64][17];
    const int m0 = blockIdx.x * 64;
    const int n0 = blockIdx.y * 64;
    const int tid = threadIdx.x;
    const int r  = tid >> 2;
    const int kq = (tid & 3) * 4;
    const int ty = tid >> 4, tx = tid & 15;
    const int bI = m0 >> 10;          // tile stays inside one batch
    const int t0 = m0 & 1023;

    float acc[4][4];
#pragma unroll
    for (int i=0;i<4;i++)
#pragma unroll
        for (int j=0;j<4;j++) acc[i][j]=0.0f;

    for (int kb = 0; kb < 1024; kb += 16){
        int kk = kb + kq;
        const float* ap = (kk < 512)
            ? h_hist + ((size_t)(t0 + r)*NB + bI)*HD + kk
            : h_hist + ((size_t)(T + t0 + r)*NB + bI)*HD + (kk - 512);
        float4 av = *(const float4*)ap;
        As[r][kq+0]=av.x; As[r][kq+1]=av.y; As[r][kq+2]=av.z; As[r][kq+3]=av.w;
        float4 bv = *(const float4*)(ws1 + (size_t)(n0 + r)*1024 + kk);
        Bs[r][kq+0]=bv.x; Bs[r][kq+1]=bv.y; Bs[r][kq+2]=bv.z; Bs[r][kq+3]=bv.w;
        __syncthreads();
#pragma unroll
        for (int k2 = 0; k2 < 16; ++k2){
            float av_[4], bv_[4];
#pragma unroll
            for (int i=0;i<4;i++) av_[i] = As[ty*4+i][k2];
#pragma unroll
            for (int j=0;j<4;j++) bv_[j] = Bs[tx*4+j][k2];
#pragma unroll
            for (int i=0;i<4;i++)
#pragma unroll
                for (int j=0;j<4;j++) acc[i][j] = fmaf(av_[i], bv_[j], acc[i][j]);
        }
        __syncthreads();
    }
#pragma unroll
    for (int i=0;i<4;i++){
        int m = m0 + ty*4 + i;
#pragma unroll
        for (int j=0;j<4;j++){
            int n = n0 + tx*4 + j;
            SH[(size_t)m*512 + n] = fmaxf(acc[i][j] + bs1[n], 0.0f);
        }
    }
}

// ---------------------------------------------------------------------------
// scores -> sigmoid -> seg_probs (ws copy + d_out)
// ---------------------------------------------------------------------------
__global__ void seg_score(const float* __restrict__ ws_, const float* __restrict__ ws2,
                          const float* __restrict__ bs2, float* __restrict__ dout)
{
    const float* SH = ws_ + OFF_SH;
    float* segp = (float*)(ws_ + OFF_SEGP);
    int row  = blockIdx.x*4 + (threadIdx.x >> 6);
    int lane = threadIdx.x & 63;
    const float* p = SH + (size_t)row*512 + lane*8;
    const float* q = ws2 + lane*8;
    float4 a0=*(const float4*)p, a1=*(const float4*)(p+4);
    float4 b0=*(const float4*)q, b1=*(const float4*)(q+4);
    float ssum = a0.x*b0.x + a0.y*b0.y + a0.z*b0.z + a0.w*b0.w
               + a1.x*b1.x + a1.y*b1.y + a1.z*b1.z + a1.w*b1.w;
#pragma unroll
    for (int m=1;m<64;m<<=1) ssum += __shfl_xor(ssum, m, 64);
    if (lane == 0){
        float z = ssum + bs2[0];
        float pr = 1.0f/(1.0f + __expf(-z));
        segp[row] = pr;
        dout[81920 + row] = pr;
    }
}

// ---------------------------------------------------------------------------
// Per-batch: mask scan (count, first-10 idx), pooled -> gctx
// ---------------------------------------------------------------------------
__global__ void select_gctx(float* __restrict__ ws_, const float* __restrict__ wgm,
                            const float* __restrict__ bgv)
{
    const float* h_hist = ws_ + OFF_HH;
    const float* segp   = ws_ + OFF_SEGP;
    float* gctx = ws_ + OFF_GCTX;
    int* sel = (int*)(ws_ + OFF_SEL);
    int b = blockIdx.x, tid = threadIdx.x;
    __shared__ unsigned char flag[1024];
    __shared__ float pool[1024];
    for (int j = tid; j < 1024; j += 256){
        flag[j] = segp[b*1024 + j] > 0.5f ? 1 : 0;
        pool[j] = (j < 512) ? h_hist[((size_t)1023*NB + b)*HD + j]
                            : h_hist[((size_t)T*NB + b)*HD + (j - 512)];
    }
    __syncthreads();
    if (tid == 0){
        int c = 0;
        int tmp[10];
        for (int j = 0; j < 10; ++j) tmp[j] = 0;
        for (int t = 0; t < 1024; ++t){
            if (flag[t]){ if (c < 10) tmp[c] = t; c++; }
        }
        for (int j = 0; j < 10; ++j) sel[b*12 + j] = tmp[j];
        sel[b*12 + 10] = c;
        sel[b*12 + 11] = 0;
    }
    __syncthreads();
    for (int n = tid; n < 1024; n += 256){
        float acc = bgv[n];
        const float* wr = wgm + (size_t)n*1024;
        for (int k = 0; k < 1024; k += 4){
            acc += wr[k]*pool[k] + wr[k+1]*pool[k+1] + wr[k+2]*pool[k+2] + wr[k+3]*pool[k+3];
        }
        gctx[b*1024 + n] = acc;
    }
}

// ---------------------------------------------------------------------------
// Decoder: one block per (b,slot)
// ---------------------------------------------------------------------------
__global__ void decode(const float* __restrict__ ws_, const float* __restrict__ wd1,
                       const float* __restrict__ bd1, const float* __restrict__ wd2,
                       const float* __restrict__ bd2, float* __restrict__ dout)
{
    const float* h_hist = ws_ + OFF_HH;
    const float* gctx   = ws_ + OFF_GCTX;
    const int* sel = (const int*)(ws_ + OFF_SEL);
    int blk = blockIdx.x;
    int b = blk / 10, slot = blk % 10;
    int tid = threadIdx.x;
    int count = sel[b*12 + 10];
    int nval = count < 10 ? count : 10;
    bool empty = (count == 0);
    float* outp = dout + (size_t)(b*10 + slot)*512;
    if (slot >= nval && !(empty && slot == 0)){
        for (int n = tid; n < 512; n += 256) outp[n] = 0.0f;
        return;
    }
    __shared__ float row[1024];
    __shared__ float dh[512];
    if (empty){
        for (int j = tid; j < 1024; j += 256) row[j] = gctx[b*1024 + j];
    } else {
        int t = sel[b*12 + slot];
        for (int j = tid; j < 1024; j += 256)
            row[j] = (j < 512) ? h_hist[((size_t)t*NB + b)*HD + j]
                               : h_hist[((size_t)(T + t)*NB + b)*HD + (j-512)];
    }
    __syncthreads();
    for (int d = tid; d < 512; d += 256){
        float acc = bd1[d];
        const float* wr = wd1 + (size_t)d*1024;
        for (int k = 0; k < 1024; ++k) acc += wr[k]*row[k];
        dh[d] = fmaxf(acc, 0.0f);
    }
    __syncthreads();
    for (int n = tid; n < 512; n += 256){
        float acc = bd2[n];
        const float* wr = wd2 + (size_t)n*512;
        for (int k = 0; k < 512; ++k) acc += wr[k]*dh[k];
        outp[n] = acc;
    }
}

extern "C" void kernel_launch(void* const* d_in, const int* in_sizes, int n_in,
                              void* d_out, int out_size, void* d_ws, size_t ws_size,
                              hipStream_t stream)
{
    const int*   instr = (const int*)d_in[0];
    const float* emb   = (const float*)d_in[1];
    const float* wih_f = (const float*)d_in[2];
    const float* whh_f = (const float*)d_in[3];
    const float* bih_f = (const float*)d_in[4];
    const float* bhh_f = (const float*)d_in[5];
    const float* wih_b = (const float*)d_in[6];
    const float* whh_b = (const float*)d_in[7];
    const float* bih_b = (const float*)d_in[8];
    const float* bhh_b = (const float*)d_in[9];
    const float* wg_   = (const float*)d_in[10];
    const float* bg_   = (const float*)d_in[11];
    const float* ws1   = (const float*)d_in[12];
    const float* bs1   = (const float*)d_in[13];
    const float* ws2   = (const float*)d_in[14];
    const float* bs2   = (const float*)d_in[15];
    const float* wd1   = (const float*)d_in[16];
    const float* bd1   = (const float*)d_in[17];
    const float* wd2   = (const float*)d_in[18];
    const float* bd2   = (const float*)d_in[19];
    float* out = (float*)d_out;
    float* ws  = (float*)d_ws;

    // zero the per-wg step flags (captured as a memset node; re-runs every replay)
    hipMemsetAsync(d_ws, 0, 1024, stream);

    hipLaunchKernelGGL(lstm_kernel, dim3(256), dim3(512), 0, stream,
                       instr, emb, wih_f, whh_f, bih_f, bhh_f,
                       wih_b, whh_b, bih_b, bhh_b, ws);
    hipLaunchKernelGGL(seg_gemm, dim3(256, 8), dim3(256), 0, stream, ws, ws1, bs1);
    hipLaunchKernelGGL(seg_score, dim3(4096), dim3(256), 0, stream, ws, ws2, bs2, out);
    hipLaunchKernelGGL(select_gctx, dim3(16), dim3(256), 0, stream, ws, wg_, bg_);
    hipLaunchKernelGGL(decode, dim3(160), dim3(256), 0, stream, ws, wd1, bd1, wd2, bd2, out);
}

// Round 8
// 4464.598 us; speedup vs baseline: 1.6493x; 1.6493x over previous
//
#include <hip/hip_runtime.h>
#include <math.h>

// Problem constants (fixed by reference)
#define T   1024
#define NB  16
#define HD  512

// ws layout (float offsets)
#define OFF_BAR  0                         // 256 ints: flag[2][4 bgrp][32 uslice]
#define OFF_HH   256                       // h_hist [2][T][NB][HD] = 16,777,216 floats
#define OFF_SH   (OFF_HH + 16777216)       // SH [16384][512] = 8,388,608 floats
#define OFF_SEGP (OFF_SH + 8388608)        // [16384]
#define OFF_GCTX (OFF_SEGP + 16384)        // [16][1024]
#define OFF_SEL  (OFF_GCTX + 16384)        // ints [16][12]

typedef unsigned long long u64;

__device__ __forceinline__ float sigmoidf_(float x){ return 1.0f/(1.0f + __expf(-x)); }
// fast tanh via exp2-based __expf; |err| ~1e-7, graceful saturation at +/-1
__device__ __forceinline__ float tanhf_(float x){ return 1.0f - 2.0f/(1.0f + __expf(2.0f*x)); }

// ---------------------------------------------------------------------------
// Persistent bidirectional LSTM. grid=256 wgs (1 per CU), block=512 (8 waves).
// NEW partition vs r4: wg -> (dir = wg&1, bgrp = (wg>>1)&3 : 4 batches,
// uslice = wg>>3 : 16 hidden units). Batches are independent sequences, so the
// h-recurrence for a batch-group closes among the 32 wgs sharing (dir,bgrp):
// 8 INDEPENDENT sync domains of 32 wgs (vs r4's 2 domains of 128).
//   - poll = 32 flags (one 128B segment), straggler max over 32 not 128
//   - all 8 waves read the SAME 4 emb rows / 4 h vectors -> L1-served dup,
//     4-8x lower L2/LLC read volume
//   - producer h-store = 4 x 64B contiguous lines (16 units per batch)
// Data path per wave = r4 verbatim: rows rg*8..+8 of the wg's 64 gate-rows
// (64 = 4 gates x 16 units), all 4 batches, k split over 64 lanes (8 k each),
// x-proj pre-poll, plain cached h loads (fresh addresses), 5-stage
// reduce-scatter + cross-half merge, LDS gbuf, wave0 gates, sc1 store ->
// vmcnt(0) -> per-wg flag.
// ---------------------------------------------------------------------------
__global__ __launch_bounds__(512, 1)
void lstm_kernel(const int* __restrict__ instr, const float* __restrict__ emb,
                 const float* __restrict__ wih_f, const float* __restrict__ whh_f,
                 const float* __restrict__ bih_f, const float* __restrict__ bhh_f,
                 const float* __restrict__ wih_b, const float* __restrict__ whh_b,
                 const float* __restrict__ bih_b, const float* __restrict__ bhh_b,
                 float* __restrict__ ws)
{
    float* h_hist = ws + OFF_HH;
    int* flags = (int*)ws;            // [2][4][32]

    const int wg     = blockIdx.x;    // 0..255
    const int dir    = wg & 1;
    const int bgrp   = (wg >> 1) & 3; // batch group: batches bgrp*4..+3
    const int uslice = wg >> 3;       // 0..31
    const int U      = uslice * 16;   // hidden-unit base (16 units per wg)
    const int b0     = bgrp * 4;

    int* barf = flags + (dir*4 + bgrp)*32;

    const float* wih = dir ? wih_b : wih_f;
    const float* whh = dir ? whh_b : whh_f;
    const float* bih = dir ? bih_b : bih_f;
    const float* bhh = dir ? bhh_b : bhh_f;

    const int tid  = threadIdx.x;
    const int wid  = tid >> 6;        // 0..7 = row-group
    const int lane = tid & 63;        // k-chunk id (8 k's per lane)
    const int rg   = wid;             // rows rg*8 .. rg*8+7 of the wg's 64

    // Load weight slices into registers: row rgl = rg*8+ri of 64
    // (gate = rgl>>4, local unit = rgl&15), k = lane*8..+8
    float wi[64], wh[64];
#pragma unroll
    for (int ri = 0; ri < 8; ++ri){
        int rgl = rg*8 + ri;
        int gate = rgl >> 4, ul = rgl & 15;
        size_t row = (size_t)(gate*HD + U + ul) * HD + lane*8;
        float4 a0 = *(const float4*)(wih + row);
        float4 a1 = *(const float4*)(wih + row + 4);
        float4 b0v = *(const float4*)(whh + row);
        float4 b1v = *(const float4*)(whh + row + 4);
        wi[ri*8+0]=a0.x; wi[ri*8+1]=a0.y; wi[ri*8+2]=a0.z; wi[ri*8+3]=a0.w;
        wi[ri*8+4]=a1.x; wi[ri*8+5]=a1.y; wi[ri*8+6]=a1.z; wi[ri*8+7]=a1.w;
        wh[ri*8+0]=b0v.x; wh[ri*8+1]=b0v.y; wh[ri*8+2]=b0v.z; wh[ri*8+3]=b0v.w;
        wh[ri*8+4]=b1v.x; wh[ri*8+5]=b1v.y; wh[ri*8+6]=b1v.z; wh[ri*8+7]=b1v.w;
    }

    // Biases for owner lanes: wave0 lane M owns (b = b0 + (M>>4), unit = U + (M&15))
    float bI, bF, bG, bO, cst = 0.0f;
    {
        int u = tid & 15;
        bI = bih[0*HD + U + u] + bhh[0*HD + U + u];
        bF = bih[1*HD + U + u] + bhh[1*HD + U + u];
        bG = bih[2*HD + U + u] + bhh[2*HD + U + u];
        bO = bih[3*HD + U + u] + bhh[3*HD + U + u];
    }

    __shared__ float gbuf[256];       // [gate][b_local*16 + ulocal]

    // reduce-scatter ownership (32 values, 5 xor stages + cross-half merge):
    // lane ends holding flat j = bitrev5(lane&31); j = bi*8 + ri
    const int jown = ((lane&1)<<4)|((lane&2)<<2)|(lane&4)|((lane&8)>>2)|((lane&16)>>4);
    const int own_bi  = jown >> 3;            // 0..3
    const int own_rgl = rg*8 + (jown & 7);    // 0..63
    const int gslot   = (own_rgl >> 4)*64 + own_bi*16 + (own_rgl & 15);

    for (int s = 0; s < T; ++s){
        const int tp = dir ? (T-1-s) : s;   // original-time index for input AND h store

        // ---- x gather + x-projection: independent of the barrier, hides latency
        float a[32];
#pragma unroll
        for (int j = 0; j < 32; ++j) a[j] = 0.0f;

#pragma unroll
        for (int bi = 0; bi < 4; ++bi){
            int b = b0 + bi;
            int idx = instr[b*T + tp];
            const float* px = emb + (size_t)idx*HD + lane*8;
            float4 x0 = *(const float4*)px;
            float4 x1 = *(const float4*)(px + 4);
            float xs[8] = {x0.x,x0.y,x0.z,x0.w,x1.x,x1.y,x1.z,x1.w};
#pragma unroll
            for (int kk = 0; kk < 8; ++kk){
                float xv = xs[kk];
#pragma unroll
                for (int ri = 0; ri < 8; ++ri)
                    a[bi*8+ri] = fmaf(xv, wi[ri*8+kk], a[bi*8+ri]);
            }
        }

        // ---- wait for step s-1 of the 32 wgs in this (dir,bgrp) domain
        if (s > 0){
            if (wid == 0){
                for (;;){
                    int v = __hip_atomic_load(barf + (lane & 31), __ATOMIC_RELAXED, __HIP_MEMORY_SCOPE_AGENT);
                    if (__all(v >= s)) break;
                    __builtin_amdgcn_s_sleep(1);
                }
            }
            __syncthreads();

            // ---- h-projection: plain cached loads (fresh per step; L1-shared
            //      across the 8 waves reading the same 4 batches)
            const int tprev = dir ? (T - s) : (s - 1);
            const float* hbase = h_hist + (size_t)(dir*T + tprev)*NB*HD;
#pragma unroll
            for (int bi = 0; bi < 4; ++bi){
                int b = b0 + bi;
                const float* ph = hbase + (size_t)b*HD + lane*8;
                float4 h0 = *(const float4*)ph;
                float4 h1 = *(const float4*)(ph + 4);
                float hs[8] = {h0.x,h0.y,h0.z,h0.w,h1.x,h1.y,h1.z,h1.w};
#pragma unroll
                for (int kk = 0; kk < 8; ++kk){
                    float hv = hs[kk];
#pragma unroll
                    for (int ri = 0; ri < 8; ++ri)
                        a[bi*8+ri] = fmaf(hv, wh[ri*8+kk], a[bi*8+ri]);
                }
            }
        }

        // ---- reduce-scatter: 32 values over 64 lanes (5 stages + merge)
#pragma unroll
        for (int m = 0; m < 5; ++m){
            const int half = 16 >> m;
            const bool up = (lane >> m) & 1;
#pragma unroll
            for (int j = 0; j < 16; ++j){
                if (j < half){
                    float lo = a[j], hi = a[j+half];
                    float rlo = __shfl_xor(lo, 1<<m, 64);
                    float rhi = __shfl_xor(hi, 1<<m, 64);
                    a[j] = up ? (hi + rhi) : (lo + rlo);
                }
            }
        }
        a[0] += __shfl_xor(a[0], 32, 64);   // cross-half k merge

        if ((lane & 32) == 0) gbuf[gslot] = a[0];
        __syncthreads();

        if (tid < 64){   // wave-uniform branch: wave0 only
            float iv = sigmoidf_(gbuf[      tid] + bI);
            float fv = sigmoidf_(gbuf[ 64 + tid] + bF);
            float gv = tanhf_  (gbuf[128 + tid] + bG);
            float ov = sigmoidf_(gbuf[192 + tid] + bO);
            cst = fv*cst + iv*gv;
            float hv = ov * tanhf_(cst);
            int b = b0 + (tid >> 4), u = tid & 15;
            // sc1 store: 16 contiguous floats per batch (64B line), 4 lines/wg
            __hip_atomic_store(&h_hist[((size_t)(dir*T + tp)*NB + b)*HD + U + u], hv,
                               __ATOMIC_RELAXED, __HIP_MEMORY_SCOPE_AGENT);
        }
        // order: h lines acked at LLC before flag store; no L2 flushes
        asm volatile("s_waitcnt vmcnt(0)" ::: "memory");
        __builtin_amdgcn_sched_barrier(0);
        if (tid == 0)
            __hip_atomic_store(barf + uslice, s + 1, __ATOMIC_RELAXED, __HIP_MEMORY_SCOPE_AGENT);
        // no trailing barrier: gbuf WAR for step s+1 is ordered by the
        // post-poll __syncthreads (wave0 reaches it only after its gbuf reads).
    }
}

// ---------------------------------------------------------------------------
// SH = relu(enc @ ws1.T + bs1)   M=16384 N=512 K=1024, fp32 64x64x16 tiles
// ---------------------------------------------------------------------------
__global__ __launch_bounds__(256, 2)
void seg_gemm(const float* __restrict__ ws_, const float* __restrict__ ws1,
              const float* __restrict__ bs1)
{
    const float* h_hist = ws_ + OFF_HH;
    float* SH = (float*)(ws_ + OFF_SH);
    __shared__ float As[64][17];
    __shared__ float Bs[64][17];
    const int m0 = blockIdx.x * 64;
    const int n0 = blockIdx.y * 64;
    const int tid = threadIdx.x;
    const int r  = tid >> 2;
    const int kq = (tid & 3) * 4;
    const int ty = tid >> 4, tx = tid & 15;
    const int bI = m0 >> 10;          // tile stays inside one batch
    const int t0 = m0 & 1023;

    float acc[4][4];
#pragma unroll
    for (int i=0;i<4;i++)
#pragma unroll
        for (int j=0;j<4;j++) acc[i][j]=0.0f;

    for (int kb = 0; kb < 1024; kb += 16){
        int kk = kb + kq;
        const float* ap = (kk < 512)
            ? h_hist + ((size_t)(t0 + r)*NB + bI)*HD + kk
            : h_hist + ((size_t)(T + t0 + r)*NB + bI)*HD + (kk - 512);
        float4 av = *(const float4*)ap;
        As[r][kq+0]=av.x; As[r][kq+1]=av.y; As[r][kq+2]=av.z; As[r][kq+3]=av.w;
        float4 bv = *(const float4*)(ws1 + (size_t)(n0 + r)*1024 + kk);
        Bs[r][kq+0]=bv.x; Bs[r][kq+1]=bv.y; Bs[r][kq+2]=bv.z; Bs[r][kq+3]=bv.w;
        __syncthreads();
#pragma unroll
        for (int k2 = 0; k2 < 16; ++k2){
            float av_[4], bv_[4];
#pragma unroll
            for (int i=0;i<4;i++) av_[i] = As[ty*4+i][k2];
#pragma unroll
            for (int j=0;j<4;j++) bv_[j] = Bs[tx*4+j][k2];
#pragma unroll
            for (int i=0;i<4;i++)
#pragma unroll
                for (int j=0;j<4;j++) acc[i][j] = fmaf(av_[i], bv_[j], acc[i][j]);
        }
        __syncthreads();
    }
#pragma unroll
    for (int i=0;i<4;i++){
        int m = m0 + ty*4 + i;
#pragma unroll
        for (int j=0;j<4;j++){
            int n = n0 + tx*4 + j;
            SH[(size_t)m*512 + n] = fmaxf(acc[i][j] + bs1[n], 0.0f);
        }
    }
}

// ---------------------------------------------------------------------------
// scores -> sigmoid -> seg_probs (ws copy + d_out)
// ---------------------------------------------------------------------------
__global__ void seg_score(const float* __restrict__ ws_, const float* __restrict__ ws2,
                          const float* __restrict__ bs2, float* __restrict__ dout)
{
    const float* SH = ws_ + OFF_SH;
    float* segp = (float*)(ws_ + OFF_SEGP);
    int row  = blockIdx.x*4 + (threadIdx.x >> 6);
    int lane = threadIdx.x & 63;
    const float* p = SH + (size_t)row*512 + lane*8;
    const float* q = ws2 + lane*8;
    float4 a0=*(const float4*)p, a1=*(const float4*)(p+4);
    float4 b0=*(const float4*)q, b1=*(const float4*)(q+4);
    float ssum = a0.x*b0.x + a0.y*b0.y + a0.z*b0.z + a0.w*b0.w
               + a1.x*b1.x + a1.y*b1.y + a1.z*b1.z + a1.w*b1.w;
#pragma unroll
    for (int m=1;m<64;m<<=1) ssum += __shfl_xor(ssum, m, 64);
    if (lane == 0){
        float z = ssum + bs2[0];
        float pr = 1.0f/(1.0f + __expf(-z));
        segp[row] = pr;
        dout[81920 + row] = pr;
    }
}

// ---------------------------------------------------------------------------
// Per-batch: mask scan (count, first-10 idx), pooled -> gctx
// ---------------------------------------------------------------------------
__global__ void select_gctx(float* __restrict__ ws_, const float* __restrict__ wgm,
                            const float* __restrict__ bgv)
{
    const float* h_hist = ws_ + OFF_HH;
    const float* segp   = ws_ + OFF_SEGP;
    float* gctx = ws_ + OFF_GCTX;
    int* sel = (int*)(ws_ + OFF_SEL);
    int b = blockIdx.x, tid = threadIdx.x;
    __shared__ unsigned char flag[1024];
    __shared__ float pool[1024];
    for (int j = tid; j < 1024; j += 256){
        flag[j] = segp[b*1024 + j] > 0.5f ? 1 : 0;
        pool[j] = (j < 512) ? h_hist[((size_t)1023*NB + b)*HD + j]
                            : h_hist[((size_t)T*NB + b)*HD + (j - 512)];
    }
    __syncthreads();
    if (tid == 0){
        int c = 0;
        int tmp[10];
        for (int j = 0; j < 10; ++j) tmp[j] = 0;
        for (int t = 0; t < 1024; ++t){
            if (flag[t]){ if (c < 10) tmp[c] = t; c++; }
        }
        for (int j = 0; j < 10; ++j) sel[b*12 + j] = tmp[j];
        sel[b*12 + 10] = c;
        sel[b*12 + 11] = 0;
    }
    __syncthreads();
    for (int n = tid; n < 1024; n += 256){
        float acc = bgv[n];
        const float* wr = wgm + (size_t)n*1024;
        for (int k = 0; k < 1024; k += 4){
            acc += wr[k]*pool[k] + wr[k+1]*pool[k+1] + wr[k+2]*pool[k+2] + wr[k+3]*pool[k+3];
        }
        gctx[b*1024 + n] = acc;
    }
}

// ---------------------------------------------------------------------------
// Decoder: one block per (b,slot)
// ---------------------------------------------------------------------------
__global__ void decode(const float* __restrict__ ws_, const float* __restrict__ wd1,
                       const float* __restrict__ bd1, const float* __restrict__ wd2,
                       const float* __restrict__ bd2, float* __restrict__ dout)
{
    const float* h_hist = ws_ + OFF_HH;
    const float* gctx   = ws_ + OFF_GCTX;
    const int* sel = (const int*)(ws_ + OFF_SEL);
    int blk = blockIdx.x;
    int b = blk / 10, slot = blk % 10;
    int tid = threadIdx.x;
    int count = sel[b*12 + 10];
    int nval = count < 10 ? count : 10;
    bool empty = (count == 0);
    float* outp = dout + (size_t)(b*10 + slot)*512;
    if (slot >= nval && !(empty && slot == 0)){
        for (int n = tid; n < 512; n += 256) outp[n] = 0.0f;
        return;
    }
    __shared__ float row[1024];
    __shared__ float dh[512];
    if (empty){
        for (int j = tid; j < 1024; j += 256) row[j] = gctx[b*1024 + j];
    } else {
        int t = sel[b*12 + slot];
        for (int j = tid; j < 1024; j += 256)
            row[j] = (j < 512) ? h_hist[((size_t)t*NB + b)*HD + j]
                               : h_hist[((size_t)(T + t)*NB + b)*HD + (j-512)];
    }
    __syncthreads();
    for (int d = tid; d < 512; d += 256){
        float acc = bd1[d];
        const float* wr = wd1 + (size_t)d*1024;
        for (int k = 0; k < 1024; ++k) acc += wr[k]*row[k];
        dh[d] = fmaxf(acc, 0.0f);
    }
    __syncthreads();
    for (int n = tid; n < 512; n += 256){
        float acc = bd2[n];
        const float* wr = wd2 + (size_t)n*512;
        for (int k = 0; k < 512; ++k) acc += wr[k]*dh[k];
        outp[n] = acc;
    }
}

extern "C" void kernel_launch(void* const* d_in, const int* in_sizes, int n_in,
                              void* d_out, int out_size, void* d_ws, size_t ws_size,
                              hipStream_t stream)
{
    const int*   instr = (const int*)d_in[0];
    const float* emb   = (const float*)d_in[1];
    const float* wih_f = (const float*)d_in[2];
    const float* whh_f = (const float*)d_in[3];
    const float* bih_f = (const float*)d_in[4];
    const float* bhh_f = (const float*)d_in[5];
    const float* wih_b = (const float*)d_in[6];
    const float* whh_b = (const float*)d_in[7];
    const float* bih_b = (const float*)d_in[8];
    const float* bhh_b = (const float*)d_in[9];
    const float* wg_   = (const float*)d_in[10];
    const float* bg_   = (const float*)d_in[11];
    const float* ws1   = (const float*)d_in[12];
    const float* bs1   = (const float*)d_in[13];
    const float* ws2   = (const float*)d_in[14];
    const float* bs2   = (const float*)d_in[15];
    const float* wd1   = (const float*)d_in[16];
    const float* bd1   = (const float*)d_in[17];
    const float* wd2   = (const float*)d_in[18];
    const float* bd2   = (const float*)d_in[19];
    float* out = (float*)d_out;
    float* ws  = (float*)d_ws;

    // zero the per-wg step flags (captured as a memset node; re-runs every replay)
    hipMemsetAsync(d_ws, 0, 1024, stream);

    hipLaunchKernelGGL(lstm_kernel, dim3(256), dim3(512), 0, stream,
                       instr, emb, wih_f, whh_f, bih_f, bhh_f,
                       wih_b, whh_b, bih_b, bhh_b, ws);
    hipLaunchKernelGGL(seg_gemm, dim3(256, 8), dim3(256), 0, stream, ws, ws1, bs1);
    hipLaunchKernelGGL(seg_score, dim3(4096), dim3(256), 0, stream, ws, ws2, bs2, out);
    hipLaunchKernelGGL(select_gctx, dim3(16), dim3(256), 0, stream, ws, wg_, bg_);
    hipLaunchKernelGGL(decode, dim3(160), dim3(256), 0, stream, ws, wd1, bd1, wd2, bd2, out);
}

// Round 10
// 4389.989 us; speedup vs baseline: 1.6774x; 1.0170x over previous
//
#include <hip/hip_runtime.h>
#include <math.h>

// Problem constants (fixed by reference)
#define T   1024
#define NB  16
#define HD  512

// ws layout (float offsets)
#define OFF_BAR  0                         // 64 floats reserved (unused)
#define OFF_HH   256                       // h_hist [2][T][NB][HD] = 16,777,216 floats
#define OFF_SH   (OFF_HH + 16777216)       // SH [16384][512] = 8,388,608 floats
#define OFF_SEGP (OFF_SH + 8388608)        // [16384]
#define OFF_GCTX (OFF_SEGP + 16384)        // [16][1024]
#define OFF_SEL  (OFF_GCTX + 16384)        // ints [16][12]

typedef unsigned long long u64;

__device__ __forceinline__ float sigmoidf_(float x){ return 1.0f/(1.0f + __expf(-x)); }
// fast tanh via exp2-based __expf; |err| ~1e-7, graceful saturation at +/-1
__device__ __forceinline__ float tanhf_(float x){ return 1.0f - 2.0f/(1.0f + __expf(2.0f*x)); }

// ---------------------------------------------------------------------------
// Persistent bidirectional LSTM. grid=256 wgs (1 per CU), block=512 (8 waves).
// Partition (r8, proven): wg -> (dir = wg&1, bgrp = (wg>>1)&3 : 4 batches,
// uslice = wg>>3 : 16 units). 8 independent sync domains of 32 wgs.
//
// Sync = canary poll-the-data, built ONLY on proven primitives (r9 lesson:
// hand-rolled sc0/sc1 asm loads deadlocked; __hip_atomic_load AGENT is the
// path r2/r4/r8 proved makes progress against remote sc1 stores):
//   - h_hist canary-armed (0xFF = -NaN, unreachable by h=o*tanh(c)) by a
//     64MB memset node per call/replay.
//   - producer wave0: 4B sc1 atomic stores, FIRE-AND-FORGET (no vmcnt ack,
//     no flag store) -> removes 2 LLC round-trip legs from the chain.
//   - consumer wave0: polls its own h input slice with 16 x u64
//     __hip_atomic_load(AGENT); all 32 floats non-canary -> data is already
//     in registers (4B stores can't tear a checked 32-bit half).
//   - wave0 relays the slice to LDS hxch[q][bi][lane] (stride-4B b32 writes,
//     conflict-free), __syncthreads releases waves 1..7 which read h from
//     LDS (~0.1us) instead of each paying an LLC round trip.
// ---------------------------------------------------------------------------
__global__ __launch_bounds__(512, 1)
void lstm_kernel(const int* __restrict__ instr, const float* __restrict__ emb,
                 const float* __restrict__ wih_f, const float* __restrict__ whh_f,
                 const float* __restrict__ bih_f, const float* __restrict__ bhh_f,
                 const float* __restrict__ wih_b, const float* __restrict__ whh_b,
                 const float* __restrict__ bih_b, const float* __restrict__ bhh_b,
                 float* __restrict__ ws)
{
    float* h_hist = ws + OFF_HH;

    const int wg     = blockIdx.x;    // 0..255
    const int dir    = wg & 1;
    const int bgrp   = (wg >> 1) & 3; // batch group: batches bgrp*4..+3
    const int uslice = wg >> 3;       // 0..31
    const int U      = uslice * 16;   // hidden-unit base (16 units per wg)
    const int b0     = bgrp * 4;

    const float* wih = dir ? wih_b : wih_f;
    const float* whh = dir ? whh_b : whh_f;
    const float* bih = dir ? bih_b : bih_f;
    const float* bhh = dir ? bhh_b : bhh_f;

    const int tid  = threadIdx.x;
    const int wid  = tid >> 6;        // 0..7 = row-group
    const int lane = tid & 63;        // k-chunk id (8 k's per lane)
    const int rg   = wid;             // rows rg*8 .. rg*8+7 of the wg's 64

    // Load weight slices into registers: row rgl = rg*8+ri of 64
    // (gate = rgl>>4, local unit = rgl&15), k = lane*8..+8
    float wi[64], wh[64];
#pragma unroll
    for (int ri = 0; ri < 8; ++ri){
        int rgl = rg*8 + ri;
        int gate = rgl >> 4, ul = rgl & 15;
        size_t row = (size_t)(gate*HD + U + ul) * HD + lane*8;
        float4 a0 = *(const float4*)(wih + row);
        float4 a1 = *(const float4*)(wih + row + 4);
        float4 b0v = *(const float4*)(whh + row);
        float4 b1v = *(const float4*)(whh + row + 4);
        wi[ri*8+0]=a0.x; wi[ri*8+1]=a0.y; wi[ri*8+2]=a0.z; wi[ri*8+3]=a0.w;
        wi[ri*8+4]=a1.x; wi[ri*8+5]=a1.y; wi[ri*8+6]=a1.z; wi[ri*8+7]=a1.w;
        wh[ri*8+0]=b0v.x; wh[ri*8+1]=b0v.y; wh[ri*8+2]=b0v.z; wh[ri*8+3]=b0v.w;
        wh[ri*8+4]=b1v.x; wh[ri*8+5]=b1v.y; wh[ri*8+6]=b1v.z; wh[ri*8+7]=b1v.w;
    }

    // Biases for owner lanes: wave0 lane M owns (b = b0 + (M>>4), unit = U + (M&15))
    float bI, bF, bG, bO, cst = 0.0f;
    {
        int u = tid & 15;
        bI = bih[0*HD + U + u] + bhh[0*HD + U + u];
        bF = bih[1*HD + U + u] + bhh[1*HD + U + u];
        bG = bih[2*HD + U + u] + bhh[2*HD + U + u];
        bO = bih[3*HD + U + u] + bhh[3*HD + U + u];
    }

    __shared__ float hxch[8*4*64];    // [q][bi][lane]: h value k=lane*8+q, batch b0+bi
    __shared__ float gbuf[256];       // [gate][b_local*16 + ulocal]

    // reduce-scatter ownership (32 values, 5 xor stages + cross-half merge):
    const int jown = ((lane&1)<<4)|((lane&2)<<2)|(lane&4)|((lane&8)>>2)|((lane&16)>>4);
    const int own_bi  = jown >> 3;            // 0..3
    const int own_rgl = rg*8 + (jown & 7);    // 0..63
    const int gslot   = (own_rgl >> 4)*64 + own_bi*16 + (own_rgl & 15);

    for (int s = 0; s < T; ++s){
        const int tp = dir ? (T-1-s) : s;   // original-time index

        // ---- x gather + x-projection: independent of the recurrence
        float a[32];
#pragma unroll
        for (int j = 0; j < 32; ++j) a[j] = 0.0f;

#pragma unroll
        for (int bi = 0; bi < 4; ++bi){
            int b = b0 + bi;
            int idx = instr[b*T + tp];
            const float* px = emb + (size_t)idx*HD + lane*8;
            float4 x0 = *(const float4*)px;
            float4 x1 = *(const float4*)(px + 4);
            float xs[8] = {x0.x,x0.y,x0.z,x0.w,x1.x,x1.y,x1.z,x1.w};
#pragma unroll
            for (int kk = 0; kk < 8; ++kk){
                float xv = xs[kk];
#pragma unroll
                for (int ri = 0; ri < 8; ++ri)
                    a[bi*8+ri] = fmaf(xv, wi[ri*8+kk], a[bi*8+ri]);
            }
        }

        if (s > 0){
            const int tprev = dir ? (T - s) : (s - 1);
            const float* hbase = h_hist + (size_t)(dir*T + tprev)*NB*HD;

            if (wid == 0){
                // ---- poll-the-data: proven AGENT atomic u64 loads until clean
                u64 pq[16];
                for (;;){
#pragma unroll
                    for (int bi = 0; bi < 4; ++bi){
                        const u64* p = (const u64*)(hbase + (size_t)(b0+bi)*HD + lane*8);
#pragma unroll
                        for (int q = 0; q < 4; ++q)
                            pq[bi*4+q] = __hip_atomic_load(p + q, __ATOMIC_RELAXED, __HIP_MEMORY_SCOPE_AGENT);
                    }
                    unsigned ok = 1u;
#pragma unroll
                    for (int j = 0; j < 16; ++j){
                        ok &= ((unsigned)(pq[j]      ) != 0xFFFFFFFFu) ? 1u : 0u;
                        ok &= ((unsigned)(pq[j] >> 32) != 0xFFFFFFFFu) ? 1u : 0u;
                    }
                    if (__all(ok != 0u)) break;
                    __builtin_amdgcn_s_sleep(1);
                }
                // ---- relay to LDS (stride-4B across lanes: conflict-free)
#pragma unroll
                for (int bi = 0; bi < 4; ++bi){
#pragma unroll
                    for (int q = 0; q < 4; ++q){
                        hxch[(2*q  )*256 + bi*64 + lane] = __uint_as_float((unsigned)(pq[bi*4+q]      ));
                        hxch[(2*q+1)*256 + bi*64 + lane] = __uint_as_float((unsigned)(pq[bi*4+q] >> 32));
                    }
                }
            }
            __syncthreads();   // releases waves 1..7; hxch visible

            // ---- h-projection from LDS (all waves; no global RT)
#pragma unroll
            for (int bi = 0; bi < 4; ++bi){
                float hs[8];
#pragma unroll
                for (int kk = 0; kk < 8; ++kk)
                    hs[kk] = hxch[kk*256 + bi*64 + lane];
#pragma unroll
                for (int kk = 0; kk < 8; ++kk){
                    float hv = hs[kk];
#pragma unroll
                    for (int ri = 0; ri < 8; ++ri)
                        a[bi*8+ri] = fmaf(hv, wh[ri*8+kk], a[bi*8+ri]);
                }
            }
        }

        // ---- reduce-scatter: 32 values over 64 lanes (5 stages + merge)
#pragma unroll
        for (int m = 0; m < 5; ++m){
            const int half = 16 >> m;
            const bool up = (lane >> m) & 1;
#pragma unroll
            for (int j = 0; j < 16; ++j){
                if (j < half){
                    float lo = a[j], hi = a[j+half];
                    float rlo = __shfl_xor(lo, 1<<m, 64);
                    float rhi = __shfl_xor(hi, 1<<m, 64);
                    a[j] = up ? (hi + rhi) : (lo + rlo);
                }
            }
        }
        a[0] += __shfl_xor(a[0], 32, 64);   // cross-half k merge

        if ((lane & 32) == 0) gbuf[gslot] = a[0];
        __syncthreads();

        if (tid < 64){   // wave-uniform branch: wave0 only
            float iv = sigmoidf_(gbuf[      tid] + bI);
            float fv = sigmoidf_(gbuf[ 64 + tid] + bF);
            float gv = tanhf_  (gbuf[128 + tid] + bG);
            float ov = sigmoidf_(gbuf[192 + tid] + bO);
            cst = fv*cst + iv*gv;
            float hv = ov * tanhf_(cst);
            int b = b0 + (tid >> 4), u = tid & 15;
            // sc1 store, FIRE-AND-FORGET: the data itself is the ready signal
            __hip_atomic_store(&h_hist[((size_t)(dir*T + tp)*NB + b)*HD + U + u], hv,
                               __ATOMIC_RELAXED, __HIP_MEMORY_SCOPE_AGENT);
        }
        // no ack, no flag, no trailing barrier:
        //  - hxch WAR: wave0 rewrites hxch only after next poll, which is after
        //    barrier2 here; waves 1..7 finished reading hxch before their gbuf
        //    writes (which precede barrier2).
        //  - gbuf WAR: waves 1..7 write gbuf(s+1) only after the post-poll
        //    barrier1(s+1), which wave0 reaches only after its gbuf reads here.
    }
}

// ---------------------------------------------------------------------------
// SH = relu(enc @ ws1.T + bs1)   M=16384 N=512 K=1024, fp32 64x64x16 tiles
// ---------------------------------------------------------------------------
__global__ __launch_bounds__(256, 2)
void seg_gemm(const float* __restrict__ ws_, const float* __restrict__ ws1,
              const float* __restrict__ bs1)
{
    const float* h_hist = ws_ + OFF_HH;
    float* SH = (float*)(ws_ + OFF_SH);
    __shared__ float As[64][17];
    __shared__ float Bs[64][17];
    const int m0 = blockIdx.x * 64;
    const int n0 = blockIdx.y * 64;
    const int tid = threadIdx.x;
    const int r  = tid >> 2;
    const int kq = (tid & 3) * 4;
    const int ty = tid >> 4, tx = tid & 15;
    const int bI = m0 >> 10;          // tile stays inside one batch
    const int t0 = m0 & 1023;

    float acc[4][4];
#pragma unroll
    for (int i=0;i<4;i++)
#pragma unroll
        for (int j=0;j<4;j++) acc[i][j]=0.0f;

    for (int kb = 0; kb < 1024; kb += 16){
        int kk = kb + kq;
        const float* ap = (kk < 512)
            ? h_hist + ((size_t)(t0 + r)*NB + bI)*HD + kk
            : h_hist + ((size_t)(T + t0 + r)*NB + bI)*HD + (kk - 512);
        float4 av = *(const float4*)ap;
        As[r][kq+0]=av.x; As[r][kq+1]=av.y; As[r][kq+2]=av.z; As[r][kq+3]=av.w;
        float4 bv = *(const float4*)(ws1 + (size_t)(n0 + r)*1024 + kk);
        Bs[r][kq+0]=bv.x; Bs[r][kq+1]=bv.y; Bs[r][kq+2]=bv.z; Bs[r][kq+3]=bv.w;
        __syncthreads();
#pragma unroll
        for (int k2 = 0; k2 < 16; ++k2){
            float av_[4], bv_[4];
#pragma unroll
            for (int i=0;i<4;i++) av_[i] = As[ty*4+i][k2];
#pragma unroll
            for (int j=0;j<4;j++) bv_[j] = Bs[tx*4+j][k2];
#pragma unroll
            for (int i=0;i<4;i++)
#pragma unroll
                for (int j=0;j<4;j++) acc[i][j] = fmaf(av_[i], bv_[j], acc[i][j]);
        }
        __syncthreads();
    }
#pragma unroll
    for (int i=0;i<4;i++){
        int m = m0 + ty*4 + i;
#pragma unroll
        for (int j=0;j<4;j++){
            int n = n0 + tx*4 + j;
            SH[(size_t)m*512 + n] = fmaxf(acc[i][j] + bs1[n], 0.0f);
        }
    }
}

// ---------------------------------------------------------------------------
// scores -> sigmoid -> seg_probs (ws copy + d_out)
// ---------------------------------------------------------------------------
__global__ void seg_score(const float* __restrict__ ws_, const float* __restrict__ ws2,
                          const float* __restrict__ bs2, float* __restrict__ dout)
{
    const float* SH = ws_ + OFF_SH;
    float* segp = (float*)(ws_ + OFF_SEGP);
    int row  = blockIdx.x*4 + (threadIdx.x >> 6);
    int lane = threadIdx.x & 63;
    const float* p = SH + (size_t)row*512 + lane*8;
    const float* q = ws2 + lane*8;
    float4 a0=*(const float4*)p, a1=*(const float4*)(p+4);
    float4 b0=*(const float4*)q, b1=*(const float4*)(q+4);
    float ssum = a0.x*b0.x + a0.y*b0.y + a0.z*b0.z + a0.w*b0.w
               + a1.x*b1.x + a1.y*b1.y + a1.z*b1.z + a1.w*b1.w;
#pragma unroll
    for (int m=1;m<64;m<<=1) ssum += __shfl_xor(ssum, m, 64);
    if (lane == 0){
        float z = ssum + bs2[0];
        float pr = 1.0f/(1.0f + __expf(-z));
        segp[row] = pr;
        dout[81920 + row] = pr;
    }
}

// ---------------------------------------------------------------------------
// Per-batch: mask scan (count, first-10 idx), pooled -> gctx
// ---------------------------------------------------------------------------
__global__ void select_gctx(float* __restrict__ ws_, const float* __restrict__ wgm,
                            const float* __restrict__ bgv)
{
    const float* h_hist = ws_ + OFF_HH;
    const float* segp   = ws_ + OFF_SEGP;
    float* gctx = ws_ + OFF_GCTX;
    int* sel = (int*)(ws_ + OFF_SEL);
    int b = blockIdx.x, tid = threadIdx.x;
    __shared__ unsigned char flag[1024];
    __shared__ float pool[1024];
    for (int j = tid; j < 1024; j += 256){
        flag[j] = segp[b*1024 + j] > 0.5f ? 1 : 0;
        pool[j] = (j < 512) ? h_hist[((size_t)1023*NB + b)*HD + j]
                            : h_hist[((size_t)T*NB + b)*HD + (j - 512)];
    }
    __syncthreads();
    if (tid == 0){
        int c = 0;
        int tmp[10];
        for (int j = 0; j < 10; ++j) tmp[j] = 0;
        for (int t = 0; t < 1024; ++t){
            if (flag[t]){ if (c < 10) tmp[c] = t; c++; }
        }
        for (int j = 0; j < 10; ++j) sel[b*12 + j] = tmp[j];
        sel[b*12 + 10] = c;
        sel[b*12 + 11] = 0;
    }
    __syncthreads();
    for (int n = tid; n < 1024; n += 256){
        float acc = bgv[n];
        const float* wr = wgm + (size_t)n*1024;
        for (int k = 0; k < 1024; k += 4){
            acc += wr[k]*pool[k] + wr[k+1]*pool[k+1] + wr[k+2]*pool[k+2] + wr[k+3]*pool[k+3];
        }
        gctx[b*1024 + n] = acc;
    }
}

// ---------------------------------------------------------------------------
// Decoder: one block per (b,slot)
// ---------------------------------------------------------------------------
__global__ void decode(const float* __restrict__ ws_, const float* __restrict__ wd1,
                       const float* __restrict__ bd1, const float* __restrict__ wd2,
                       const float* __restrict__ bd2, float* __restrict__ dout)
{
    const float* h_hist = ws_ + OFF_HH;
    const float* gctx   = ws_ + OFF_GCTX;
    const int* sel = (const int*)(ws_ + OFF_SEL);
    int blk = blockIdx.x;
    int b = blk / 10, slot = blk % 10;
    int tid = threadIdx.x;
    int count = sel[b*12 + 10];
    int nval = count < 10 ? count : 10;
    bool empty = (count == 0);
    float* outp = dout + (size_t)(b*10 + slot)*512;
    if (slot >= nval && !(empty && slot == 0)){
        for (int n = tid; n < 512; n += 256) outp[n] = 0.0f;
        return;
    }
    __shared__ float row[1024];
    __shared__ float dh[512];
    if (empty){
        for (int j = tid; j < 1024; j += 256) row[j] = gctx[b*1024 + j];
    } else {
        int t = sel[b*12 + slot];
        for (int j = tid; j < 1024; j += 256)
            row[j] = (j < 512) ? h_hist[((size_t)t*NB + b)*HD + j]
                               : h_hist[((size_t)(T + t)*NB + b)*HD + (j-512)];
    }
    __syncthreads();
    for (int d = tid; d < 512; d += 256){
        float acc = bd1[d];
        const float* wr = wd1 + (size_t)d*1024;
        for (int k = 0; k < 1024; ++k) acc += wr[k]*row[k];
        dh[d] = fmaxf(acc, 0.0f);
    }
    __syncthreads();
    for (int n = tid; n < 512; n += 256){
        float acc = bd2[n];
        const float* wr = wd2 + (size_t)n*512;
        for (int k = 0; k < 512; ++k) acc += wr[k]*dh[k];
        outp[n] = acc;
    }
}

extern "C" void kernel_launch(void* const* d_in, const int* in_sizes, int n_in,
                              void* d_out, int out_size, void* d_ws, size_t ws_size,
                              hipStream_t stream)
{
    const int*   instr = (const int*)d_in[0];
    const float* emb   = (const float*)d_in[1];
    const float* wih_f = (const float*)d_in[2];
    const float* whh_f = (const float*)d_in[3];
    const float* bih_f = (const float*)d_in[4];
    const float* bhh_f = (const float*)d_in[5];
    const float* wih_b = (const float*)d_in[6];
    const float* whh_b = (const float*)d_in[7];
    const float* bih_b = (const float*)d_in[8];
    const float* bhh_b = (const float*)d_in[9];
    const float* wg_   = (const float*)d_in[10];
    const float* bg_   = (const float*)d_in[11];
    const float* ws1   = (const float*)d_in[12];
    const float* bs1   = (const float*)d_in[13];
    const float* ws2   = (const float*)d_in[14];
    const float* bs2   = (const float*)d_in[15];
    const float* wd1   = (const float*)d_in[16];
    const float* bd1   = (const float*)d_in[17];
    const float* wd2   = (const float*)d_in[18];
    const float* bd2   = (const float*)d_in[19];
    float* out = (float*)d_out;
    float* ws  = (float*)d_ws;

    // canary-arm the h exchange buffer (0xFF = -NaN; re-arms every replay)
    hipMemsetAsync((char*)d_ws + (size_t)OFF_HH*4, 0xFF, (size_t)16777216*4, stream);

    hipLaunchKernelGGL(lstm_kernel, dim3(256), dim3(512), 0, stream,
                       instr, emb, wih_f, whh_f, bih_f, bhh_f,
                       wih_b, whh_b, bih_b, bhh_b, ws);
    hipLaunchKernelGGL(seg_gemm, dim3(256, 8), dim3(256), 0, stream, ws, ws1, bs1);
    hipLaunchKernelGGL(seg_score, dim3(4096), dim3(256), 0, stream, ws, ws2, bs2, out);
    hipLaunchKernelGGL(select_gctx, dim3(16), dim3(256), 0, stream, ws, wg_, bg_);
    hipLaunchKernelGGL(decode, dim3(160), dim3(256), 0, stream, ws, wd1, bd1, wd2, bd2, out);
}